// Round 1
// baseline (3091.073 us; speedup 1.0000x reference)
//
#include <hip/hip_runtime.h>
#include <hip/hip_bf16.h>

#define BB   2
#define HH   256
#define WWD  256
#define CC   192
#define WSZ  8
#define TT   64
#define NHD  6
#define DHD  32
#define N3   576

// ---------------- kernel 1: spatial sum of x -> sums[b][c] ----------------
__global__ __launch_bounds__(256) void lcam_sum_x(const float* __restrict__ x,
                                                  float* __restrict__ sums) {
  int blk = blockIdx.x;            // 1024 blocks: 2 batches * 512 chunks of 128 px
  int b = blk >> 9;
  int chunk = blk & 511;
  const float* xp = x + ((size_t)b * 65536 + (size_t)chunk * 128) * CC;
  int t = threadIdx.x;
  if (t < CC) {
    float acc = 0.f;
    for (int p = 0; p < 128; ++p) acc += xp[(size_t)p * CC + t];
    atomicAdd(&sums[b * CC + t], acc);
  }
}

// ---------------- kernel 2: global token gt[b][c] ----------------
__global__ void lcam_gt(const float* __restrict__ sums,
                        const float* __restrict__ gt_w,
                        const float* __restrict__ gt_b,
                        float* __restrict__ gt) {
  int b = blockIdx.x;
  int co = threadIdx.x;            // 192 threads
  float acc = gt_b[co];
  const float inv = 1.f / 65536.f;
  for (int c = 0; c < CC; ++c)
    acc += sums[b * CC + c] * inv * gt_w[c * CC + co];
  gt[b * CC + co] = acc;
}

// ---------------- kernel 3: fused window attention (writes pre-proj out) ----
__global__ __launch_bounds__(256) void lcam_attn(
    const float* __restrict__ x, const float* __restrict__ illu,
    const float* __restrict__ qkv_w, const float* __restrict__ qkv_b,
    const float* __restrict__ gt, float* __restrict__ out) {
  __shared__ __align__(16) float smem[9096];
  float* xs = smem;            // [64][33]  x K-chunk
  float* qs = smem + 2112;     // [64][36]
  float* ks = smem + 4416;     // [65][36]
  float* vs = smem + 6756;     // [65][36]

  int w = blockIdx.x;          // 2048 windows
  int b  = w >> 10;
  int wy = (w >> 5) & 31;
  int wx = w & 31;
  int t  = threadIdx.x;
  int rg = t >> 4, cg = t & 15;   // GEMM tiling: 16 row-groups x 16 col-groups
  int row = t >> 2, p = t & 3;    // attention: 64 rows x 4 lanes

  size_t base = ((size_t)(b * HH + wy * WSZ) * WWD + wx * WSZ) * CC;
  size_t rowoff = base + (size_t)((row >> 3) * WWD + (row & 7)) * CC;

  for (int h = 0; h < NHD; ++h) {
    // ---- qkv GEMM for this head: 64 x 96 (q|k|v), K = 192 ----
    int colIdx[6];
#pragma unroll
    for (int jj = 0; jj < 6; ++jj) {
      int j = cg * 6 + jj;
      colIdx[jj] = (j >> 5) * CC + h * DHD + (j & 31);
    }
    float acc[4][6];
#pragma unroll
    for (int i = 0; i < 4; ++i)
#pragma unroll
      for (int jj = 0; jj < 6; ++jj) acc[i][jj] = 0.f;

    for (int c6 = 0; c6 < 6; ++c6) {
      int kb = c6 * 32;
      __syncthreads();
      // stage x chunk: 64 px x 32 ch, float4 loads
#pragma unroll
      for (int rr = 0; rr < 2; ++rr) {
        int vi = t + rr * 256;
        int pix = vi >> 3;
        int cq = vi & 7;
        const float4 v4 = *(const float4*)(x + base +
            (size_t)(((pix >> 3) * WWD) + (pix & 7)) * CC + kb + cq * 4);
        float* d = xs + pix * 33 + cq * 4;
        d[0] = v4.x; d[1] = v4.y; d[2] = v4.z; d[3] = v4.w;
      }
      __syncthreads();
      const float* wbase = qkv_w + (size_t)kb * N3;
#pragma unroll 4
      for (int kk = 0; kk < 32; ++kk) {
        const float* wr = wbase + (size_t)kk * N3;
        float a0 = xs[(rg * 4 + 0) * 33 + kk];
        float a1 = xs[(rg * 4 + 1) * 33 + kk];
        float a2 = xs[(rg * 4 + 2) * 33 + kk];
        float a3 = xs[(rg * 4 + 3) * 33 + kk];
#pragma unroll
        for (int jj = 0; jj < 6; ++jj) {
          float wv = wr[colIdx[jj]];
          acc[0][jj] += a0 * wv;
          acc[1][jj] += a1 * wv;
          acc[2][jj] += a2 * wv;
          acc[3][jj] += a3 * wv;
        }
      }
    }
    __syncthreads();
    // scatter to qs/ks/vs (+bias)
#pragma unroll
    for (int jj = 0; jj < 6; ++jj) {
      int j = cg * 6 + jj;
      int sect = j >> 5;
      int within = j & 31;
      float bias = qkv_b[colIdx[jj]];
      float* dst = (sect == 0) ? qs : ((sect == 1) ? ks : vs);
#pragma unroll
      for (int i = 0; i < 4; ++i)
        dst[(rg * 4 + i) * 36 + within] = acc[i][jj] + bias;
    }
    __syncthreads();
    // normalize q row (L2 over 32, eps like F.normalize)
    {
      float ss = 0.f;
#pragma unroll
      for (int i = 0; i < 8; ++i) { float v = qs[row * 36 + p * 8 + i]; ss += v * v; }
      ss += __shfl_xor(ss, 1); ss += __shfl_xor(ss, 2);
      float scl = 1.f / fmaxf(sqrtf(ss), 1e-12f);
#pragma unroll
      for (int i = 0; i < 8; ++i) qs[row * 36 + p * 8 + i] *= scl;
    }
    // normalize k row
    {
      float ss = 0.f;
#pragma unroll
      for (int i = 0; i < 8; ++i) { float v = ks[row * 36 + p * 8 + i]; ss += v * v; }
      ss += __shfl_xor(ss, 1); ss += __shfl_xor(ss, 2);
      float scl = 1.f / fmaxf(sqrtf(ss), 1e-12f);
#pragma unroll
      for (int i = 0; i < 8; ++i) ks[row * 36 + p * 8 + i] *= scl;
    }
    // modulate v with 1 + sigmoid(illu)
    {
      const float* ip = illu + rowoff + h * DHD + p * 8;
#pragma unroll
      for (int i = 0; i < 8; ++i) {
        float il = ip[i];
        float sg = 1.f / (1.f + expf(-il));
        vs[row * 36 + p * 8 + i] *= (1.f + sg);
      }
    }
    // global token row (65th key/value) -- raw gt, NOT normalized/modulated
    if (t < DHD) {
      float g = gt[b * CC + h * DHD + t];
      ks[64 * 36 + t] = g;
      vs[64 * 36 + t] = g;
    }
    __syncthreads();
    // ---- scores (row handled by 4 lanes; lane p owns keys j = p + 4m) ----
    float qreg[32];
#pragma unroll
    for (int q4 = 0; q4 < 8; ++q4) {
      float4 v = *(const float4*)(qs + row * 36 + q4 * 4);
      qreg[q4 * 4 + 0] = v.x; qreg[q4 * 4 + 1] = v.y;
      qreg[q4 * 4 + 2] = v.z; qreg[q4 * 4 + 3] = v.w;
    }
    float scv[17];
    float mx = -1e30f;
#pragma unroll
    for (int m = 0; m < 17; ++m) {
      int j = p + 4 * m;
      float d = -1e30f;
      if (j < 65) {
        const float* kr = ks + j * 36;
        float s = 0.f;
#pragma unroll
        for (int q4 = 0; q4 < 8; ++q4) {
          float4 kv = *(const float4*)(kr + q4 * 4);
          s += qreg[q4 * 4 + 0] * kv.x + qreg[q4 * 4 + 1] * kv.y +
               qreg[q4 * 4 + 2] * kv.z + qreg[q4 * 4 + 3] * kv.w;
        }
        d = s * 0.17677669529663688f;   // 1/sqrt(32)
        mx = fmaxf(mx, d);
      }
      scv[m] = d;
    }
    mx = fmaxf(mx, __shfl_xor(mx, 1));
    mx = fmaxf(mx, __shfl_xor(mx, 2));
    float sum = 0.f;
#pragma unroll
    for (int m = 0; m < 17; ++m) {
      float e = (scv[m] > -1e29f) ? expf(scv[m] - mx) : 0.f;
      scv[m] = e;
      sum += e;
    }
    sum += __shfl_xor(sum, 1);
    sum += __shfl_xor(sum, 2);
    float inv = 1.f / sum;
#pragma unroll
    for (int m = 0; m < 17; ++m) scv[m] *= inv;
    // ---- PV: lane p accumulates dims p*8..p*8+7 over all 65 keys ----
    float oacc8[8];
#pragma unroll
    for (int i = 0; i < 8; ++i) oacc8[i] = 0.f;
    int lbase = t & 60;   // lane base of this 4-lane group within the wave
#pragma unroll
    for (int j = 0; j < 65; ++j) {
      float a = __shfl(scv[j >> 2], lbase | (j & 3));
      const float* vr = vs + j * 36 + p * 8;
      float4 v0 = *(const float4*)(vr);
      float4 v1 = *(const float4*)(vr + 4);
      oacc8[0] += a * v0.x; oacc8[1] += a * v0.y;
      oacc8[2] += a * v0.z; oacc8[3] += a * v0.w;
      oacc8[4] += a * v1.x; oacc8[5] += a * v1.y;
      oacc8[6] += a * v1.z; oacc8[7] += a * v1.w;
    }
    float4 o0 = {oacc8[0], oacc8[1], oacc8[2], oacc8[3]};
    float4 o1 = {oacc8[4], oacc8[5], oacc8[6], oacc8[7]};
    *(float4*)(out + rowoff + h * DHD + p * 8) = o0;
    *(float4*)(out + rowoff + h * DHD + p * 8 + 4) = o1;
  }
}

// ---------------- kernel 4: in-place per-pixel projection ----------------
__global__ __launch_bounds__(256) void lcam_proj(const float* __restrict__ proj_w,
                                                 const float* __restrict__ proj_b,
                                                 float* __restrict__ out) {
  __shared__ __align__(16) float aw[64 * 196];
  int blk = blockIdx.x;                 // 2048 blocks x 64 pixels
  size_t pbase = (size_t)blk * 64 * CC;
  int t = threadIdx.x;
  for (int vi = t; vi < 3072; vi += 256) {   // 64*192/4 float4s
    int pix = vi / 48;
    int c4 = vi % 48;
    float4 v = *(const float4*)(out + pbase + (size_t)pix * CC + c4 * 4);
    *(float4*)(aw + pix * 196 + c4 * 4) = v;
  }
  __syncthreads();
  int rg = t >> 4, cg = t & 15;   // rows rg*4..+3, cols cg*12..+11
  float bias[12];
#pragma unroll
  for (int jj = 0; jj < 12; ++jj) bias[jj] = proj_b[cg * 12 + jj];
  float pacc[4][12];
#pragma unroll
  for (int i = 0; i < 4; ++i)
#pragma unroll
    for (int jj = 0; jj < 12; ++jj) pacc[i][jj] = 0.f;
#pragma unroll 4
  for (int kk = 0; kk < CC; ++kk) {
    float a0 = aw[(rg * 4 + 0) * 196 + kk];
    float a1 = aw[(rg * 4 + 1) * 196 + kk];
    float a2 = aw[(rg * 4 + 2) * 196 + kk];
    float a3 = aw[(rg * 4 + 3) * 196 + kk];
    const float* wr = proj_w + (size_t)kk * CC + cg * 12;
#pragma unroll
    for (int jj = 0; jj < 12; ++jj) {
      float wv = wr[jj];
      pacc[0][jj] += a0 * wv;
      pacc[1][jj] += a1 * wv;
      pacc[2][jj] += a2 * wv;
      pacc[3][jj] += a3 * wv;
    }
  }
#pragma unroll
  for (int i = 0; i < 4; ++i) {
    size_t o = pbase + (size_t)(rg * 4 + i) * CC + cg * 12;
#pragma unroll
    for (int jj = 0; jj < 12; ++jj) out[o + jj] = pacc[i][jj] + bias[jj];
  }
}

// ------------- kernel 5: dwconv -> gelu -> dwconv, += into out -------------
__global__ __launch_bounds__(256) void lcam_pos(const float* __restrict__ x,
                                                const float* __restrict__ w1,
                                                const float* __restrict__ w2,
                                                float* __restrict__ out) {
  __shared__ __align__(16) float xt[20 * 20 * 16];
  __shared__ float t1[18 * 18 * 16];
  __shared__ float wl1[16 * 9], wl2[16 * 9];
  int blk = blockIdx.x;             // b(2) * ty(16) * tx(16) * cg(12)
  int cgI = blk % 12; int tmp = blk / 12;
  int tx = tmp % 16; tmp /= 16;
  int ty = tmp % 16; int b = tmp / 16;
  int c0 = cgI * 16;
  int y0 = ty * 16, x0 = tx * 16;
  int t = threadIdx.x;
  if (t < 144) { wl1[t] = w1[c0 * 9 + t]; wl2[t] = w2[c0 * 9 + t]; }
  // stage x halo 20x20x16 (zero outside image = SAME zero pad)
  for (int vi = t; vi < 1600; vi += 256) {
    int cc4 = vi & 3;
    int lin = vi >> 2;
    int xx = lin % 20, yy = lin / 20;
    int gy = y0 - 2 + yy, gx = x0 - 2 + xx;
    float4 v = {0.f, 0.f, 0.f, 0.f};
    if (gy >= 0 && gy < HH && gx >= 0 && gx < WWD)
      v = *(const float4*)(x + (((size_t)b * HH + gy) * WWD + gx) * CC + c0 + cc4 * 4);
    *(float4*)(xt + (yy * 20 + xx) * 16 + cc4 * 4) = v;
  }
  __syncthreads();
  // conv1 + exact gelu -> t1 halo 18x18x16; force 0 outside image (conv2 zero-pads)
  for (int idx = t; idx < 5184; idx += 256) {
    int cc = idx & 15;
    int xx = (idx >> 4) % 18;
    int yy = idx / 288;
    int gy = y0 - 1 + yy, gx = x0 - 1 + xx;
    float r = 0.f;
    if (gy >= 0 && gy < HH && gx >= 0 && gx < WWD) {
#pragma unroll
      for (int ky = 0; ky < 3; ++ky)
#pragma unroll
        for (int kx = 0; kx < 3; ++kx)
          r += xt[((yy + ky) * 20 + xx + kx) * 16 + cc] * wl1[cc * 9 + ky * 3 + kx];
      r = 0.5f * r * (1.f + erff(r * 0.70710678118654752f));
    }
    t1[(yy * 18 + xx) * 16 + cc] = r;
  }
  __syncthreads();
  // conv2 + add into out
  for (int idx = t; idx < 4096; idx += 256) {
    int cc = idx & 15;
    int xx = (idx >> 4) & 15;
    int yy = idx >> 8;
    float r = 0.f;
#pragma unroll
    for (int ky = 0; ky < 3; ++ky)
#pragma unroll
      for (int kx = 0; kx < 3; ++kx)
        r += t1[((yy + ky) * 18 + xx + kx) * 16 + cc] * wl2[cc * 9 + ky * 3 + kx];
    size_t o = (((size_t)b * HH + y0 + yy) * WWD + x0 + xx) * CC + c0 + cc;
    out[o] += r;
  }
}

extern "C" void kernel_launch(void* const* d_in, const int* in_sizes, int n_in,
                              void* d_out, int out_size, void* d_ws, size_t ws_size,
                              hipStream_t stream) {
  const float* x       = (const float*)d_in[0];
  const float* illu    = (const float*)d_in[1];
  const float* gt_w    = (const float*)d_in[2];
  const float* gt_b    = (const float*)d_in[3];
  const float* qkv_w   = (const float*)d_in[4];
  const float* qkv_b   = (const float*)d_in[5];
  const float* proj_w  = (const float*)d_in[6];
  const float* proj_b  = (const float*)d_in[7];
  const float* conv1_w = (const float*)d_in[8];
  const float* conv2_w = (const float*)d_in[9];
  float* out = (float*)d_out;
  float* sums = (float*)d_ws;           // B*C floats
  float* gt   = sums + BB * CC;         // B*C floats

  hipMemsetAsync(d_ws, 0, BB * CC * sizeof(float), stream);
  lcam_sum_x<<<1024, 256, 0, stream>>>(x, sums);
  lcam_gt<<<BB, CC, 0, stream>>>(sums, gt_w, gt_b, gt);
  lcam_attn<<<2048, 256, 0, stream>>>(x, illu, qkv_w, qkv_b, gt, out);
  lcam_proj<<<2048, 256, 0, stream>>>(proj_w, proj_b, out);
  lcam_pos<<<6144, 256, 0, stream>>>(x, conv1_w, conv2_w, out);
}

// Round 2
// 782.292 us; speedup vs baseline: 3.9513x; 3.9513x over previous
//
#include <hip/hip_runtime.h>
#include <hip/hip_bf16.h>

#define BB   2
#define HH   256
#define WWD  256
#define CC   192
#define WSZ  8
#define TT   64
#define NHD  6
#define DHD  32
#define N3   576

typedef __attribute__((ext_vector_type(8))) short short8;
typedef __attribute__((ext_vector_type(4))) float f32x4;

__device__ inline short bf16_bits(float f) {
  __hip_bfloat16 h = __float2bfloat16(f);
  return __builtin_bit_cast(short, h);
}

// ---------------- kernel 0: pre-shuffle qkv_w into bf16 B-fragment layout ---
// frag index gid = ct*384 + s*64 + lane; element j: B[k = s*32 + (lane>>4)*8 + j]
//                                                  [col = ct*16 + (lane&15)]
__global__ __launch_bounds__(256) void lcam_wshuf(const float* __restrict__ qkv_w,
                                                  short* __restrict__ wf) {
  int gid = blockIdx.x * 256 + threadIdx.x;
  if (gid >= 36 * 6 * 64) return;
  int lane = gid & 63;
  int s = (gid >> 6) % 6;
  int ct = gid / 384;
  int col = ct * 16 + (lane & 15);
  int k0 = s * 32 + (lane >> 4) * 8;
  short8 v;
#pragma unroll
  for (int j = 0; j < 8; ++j)
    v[j] = bf16_bits(qkv_w[(size_t)(k0 + j) * N3 + col]);
  *(short8*)(wf + (size_t)gid * 8) = v;
}

// ---------------- kernel 1: spatial sum of x -> sums[b][c] ----------------
__global__ __launch_bounds__(256) void lcam_sum_x(const float* __restrict__ x,
                                                  float* __restrict__ sums) {
  int blk = blockIdx.x;            // 1024 blocks: 2 batches * 512 chunks of 128 px
  int b = blk >> 9;
  int chunk = blk & 511;
  const float* xp = x + ((size_t)b * 65536 + (size_t)chunk * 128) * CC;
  int t = threadIdx.x;
  if (t < CC) {
    float acc = 0.f;
    for (int p = 0; p < 128; ++p) acc += xp[(size_t)p * CC + t];
    atomicAdd(&sums[b * CC + t], acc);
  }
}

// ---------------- kernel 2: global token gt[b][c] ----------------
__global__ void lcam_gt(const float* __restrict__ sums,
                        const float* __restrict__ gt_w,
                        const float* __restrict__ gt_b,
                        float* __restrict__ gt) {
  int b = blockIdx.x;
  int co = threadIdx.x;            // 192 threads
  float acc = gt_b[co];
  const float inv = 1.f / 65536.f;
  for (int c = 0; c < CC; ++c)
    acc += sums[b * CC + c] * inv * gt_w[c * CC + co];
  gt[b * CC + co] = acc;
}

// ------------- kernel 3: fused window attention, qkv GEMM via bf16 MFMA -----
__global__ __launch_bounds__(256) void lcam_attn(
    const float* __restrict__ x, const float* __restrict__ illu,
    const short* __restrict__ wf, const float* __restrict__ qkv_b,
    const float* __restrict__ gt, float* __restrict__ out) {
  __shared__ __align__(16) float qs[64 * 36];
  __shared__ __align__(16) float ks[65 * 36];
  __shared__ __align__(16) float vs[65 * 36];

  int w = blockIdx.x;          // 2048 windows
  int b  = w >> 10;
  int wy = (w >> 5) & 31;
  int wx = w & 31;
  int t  = threadIdx.x;
  int lane = t & 63;
  int rtile = t >> 6;             // wave id = 16-row tile
  int m = lane & 15;              // MFMA row/col within tile
  int quad = lane >> 4;
  int row = t >> 2, p = t & 3;    // attention phase: 64 rows x 4 lanes

  size_t base = ((size_t)(b * HH + wy * WSZ) * WWD + wx * WSZ) * CC;
  size_t rowoff = base + (size_t)((row >> 3) * WWD + (row & 7)) * CC;

  // ---- preload A-fragments of x (bf16), reused across all heads ----
  int pix = rtile * 16 + m;
  size_t arow = base + (size_t)((pix >> 3) * WWD + (pix & 7)) * CC + quad * 8;
  short8 afrag[6];
#pragma unroll
  for (int s = 0; s < 6; ++s) {
    const float* ap = x + arow + s * 32;
    float4 f0 = *(const float4*)(ap);
    float4 f1 = *(const float4*)(ap + 4);
    short8 v;
    v[0] = bf16_bits(f0.x); v[1] = bf16_bits(f0.y);
    v[2] = bf16_bits(f0.z); v[3] = bf16_bits(f0.w);
    v[4] = bf16_bits(f1.x); v[5] = bf16_bits(f1.y);
    v[6] = bf16_bits(f1.z); v[7] = bf16_bits(f1.w);
    afrag[s] = v;
  }
  const short8* wf8 = (const short8*)wf;

  for (int h = 0; h < NHD; ++h) {
    // ---- qkv GEMM: D[64x16] tiles, q/k/v sections, K=192 in 6 MFMA steps ----
#pragma unroll
    for (int part = 0; part < 3; ++part) {
      float* dst = (part == 0) ? qs : ((part == 1) ? ks : vs);
#pragma unroll
      for (int half = 0; half < 2; ++half) {
        int ct = part * 12 + 2 * h + half;
        f32x4 acc = {0.f, 0.f, 0.f, 0.f};
#pragma unroll
        for (int s = 0; s < 6; ++s) {
          short8 bfrag = wf8[ct * 384 + s * 64 + lane];
          acc = __builtin_amdgcn_mfma_f32_16x16x32_bf16(afrag[s], bfrag, acc, 0, 0, 0);
        }
        float bias = qkv_b[part * 192 + h * 32 + half * 16 + m];
        // C/D layout: col = lane&15 (=m), row = quad*4 + reg
#pragma unroll
        for (int r = 0; r < 4; ++r)
          dst[(rtile * 16 + quad * 4 + r) * 36 + half * 16 + m] = acc[r] + bias;
      }
    }
    // global token row (65th key/value) -- raw gt, NOT normalized/modulated
    if (t < DHD) {
      float g = gt[b * CC + h * DHD + t];
      ks[64 * 36 + t] = g;
      vs[64 * 36 + t] = g;
    }
    // ---- same-wave in-place epilogue (wave's own 16 rows; ds ops in-order) --
    // normalize q row (L2 over 32, eps like F.normalize)
    {
      float ss = 0.f;
#pragma unroll
      for (int i = 0; i < 8; ++i) { float v = qs[row * 36 + p * 8 + i]; ss += v * v; }
      ss += __shfl_xor(ss, 1); ss += __shfl_xor(ss, 2);
      float scl = 1.f / fmaxf(sqrtf(ss), 1e-12f);
#pragma unroll
      for (int i = 0; i < 8; ++i) qs[row * 36 + p * 8 + i] *= scl;
    }
    // normalize k row
    {
      float ss = 0.f;
#pragma unroll
      for (int i = 0; i < 8; ++i) { float v = ks[row * 36 + p * 8 + i]; ss += v * v; }
      ss += __shfl_xor(ss, 1); ss += __shfl_xor(ss, 2);
      float scl = 1.f / fmaxf(sqrtf(ss), 1e-12f);
#pragma unroll
      for (int i = 0; i < 8; ++i) ks[row * 36 + p * 8 + i] *= scl;
    }
    // modulate v with 1 + sigmoid(illu)
    {
      const float* ip = illu + rowoff + h * DHD + p * 8;
#pragma unroll
      for (int i = 0; i < 8; ++i) {
        float il = ip[i];
        float sg = 1.f / (1.f + expf(-il));
        vs[row * 36 + p * 8 + i] *= (1.f + sg);
      }
    }
    __syncthreads();
    // ---- scores (row handled by 4 lanes; lane p owns keys j = p + 4m) ----
    float qreg[32];
#pragma unroll
    for (int q4 = 0; q4 < 8; ++q4) {
      float4 v = *(const float4*)(qs + row * 36 + q4 * 4);
      qreg[q4 * 4 + 0] = v.x; qreg[q4 * 4 + 1] = v.y;
      qreg[q4 * 4 + 2] = v.z; qreg[q4 * 4 + 3] = v.w;
    }
    float scv[17];
    float mx = -1e30f;
#pragma unroll
    for (int mm = 0; mm < 17; ++mm) {
      int j = p + 4 * mm;
      float d = -1e30f;
      if (j < 65) {
        const float* kr = ks + j * 36;
        float s = 0.f;
#pragma unroll
        for (int q4 = 0; q4 < 8; ++q4) {
          float4 kv = *(const float4*)(kr + q4 * 4);
          s += qreg[q4 * 4 + 0] * kv.x + qreg[q4 * 4 + 1] * kv.y +
               qreg[q4 * 4 + 2] * kv.z + qreg[q4 * 4 + 3] * kv.w;
        }
        d = s * 0.17677669529663688f;   // 1/sqrt(32)
        mx = fmaxf(mx, d);
      }
      scv[mm] = d;
    }
    mx = fmaxf(mx, __shfl_xor(mx, 1));
    mx = fmaxf(mx, __shfl_xor(mx, 2));
    float sum = 0.f;
#pragma unroll
    for (int mm = 0; mm < 17; ++mm) {
      float e = (scv[mm] > -1e29f) ? expf(scv[mm] - mx) : 0.f;
      scv[mm] = e;
      sum += e;
    }
    sum += __shfl_xor(sum, 1);
    sum += __shfl_xor(sum, 2);
    float inv = 1.f / sum;
#pragma unroll
    for (int mm = 0; mm < 17; ++mm) scv[mm] *= inv;
    // ---- PV: lane p accumulates dims p*8..p*8+7 over all 65 keys ----
    float oacc8[8];
#pragma unroll
    for (int i = 0; i < 8; ++i) oacc8[i] = 0.f;
    int lbase = t & 60;   // lane base of this 4-lane group within the wave
#pragma unroll
    for (int j = 0; j < 65; ++j) {
      float a = __shfl(scv[j >> 2], lbase | (j & 3));
      const float* vr = vs + j * 36 + p * 8;
      float4 v0 = *(const float4*)(vr);
      float4 v1 = *(const float4*)(vr + 4);
      oacc8[0] += a * v0.x; oacc8[1] += a * v0.y;
      oacc8[2] += a * v0.z; oacc8[3] += a * v0.w;
      oacc8[4] += a * v1.x; oacc8[5] += a * v1.y;
      oacc8[6] += a * v1.z; oacc8[7] += a * v1.w;
    }
    float4 o0 = {oacc8[0], oacc8[1], oacc8[2], oacc8[3]};
    float4 o1 = {oacc8[4], oacc8[5], oacc8[6], oacc8[7]};
    *(float4*)(out + rowoff + h * DHD + p * 8) = o0;
    *(float4*)(out + rowoff + h * DHD + p * 8 + 4) = o1;
    __syncthreads();   // vs/ks reused next head
  }
}

// ---------------- kernel 4: in-place per-pixel projection ----------------
__global__ __launch_bounds__(256) void lcam_proj(const float* __restrict__ proj_w,
                                                 const float* __restrict__ proj_b,
                                                 float* __restrict__ out) {
  __shared__ __align__(16) float aw[64 * 196];
  int blk = blockIdx.x;                 // 2048 blocks x 64 pixels
  size_t pbase = (size_t)blk * 64 * CC;
  int t = threadIdx.x;
  for (int vi = t; vi < 3072; vi += 256) {   // 64*192/4 float4s
    int pix = vi / 48;
    int c4 = vi % 48;
    float4 v = *(const float4*)(out + pbase + (size_t)pix * CC + c4 * 4);
    *(float4*)(aw + pix * 196 + c4 * 4) = v;
  }
  __syncthreads();
  int rg = t >> 4, cg = t & 15;   // rows rg*4..+3, cols cg*12..+11
  float bias[12];
#pragma unroll
  for (int jj = 0; jj < 12; ++jj) bias[jj] = proj_b[cg * 12 + jj];
  float pacc[4][12];
#pragma unroll
  for (int i = 0; i < 4; ++i)
#pragma unroll
    for (int jj = 0; jj < 12; ++jj) pacc[i][jj] = 0.f;
#pragma unroll 4
  for (int kk = 0; kk < CC; ++kk) {
    float a0 = aw[(rg * 4 + 0) * 196 + kk];
    float a1 = aw[(rg * 4 + 1) * 196 + kk];
    float a2 = aw[(rg * 4 + 2) * 196 + kk];
    float a3 = aw[(rg * 4 + 3) * 196 + kk];
    const float* wr = proj_w + (size_t)kk * CC + cg * 12;
#pragma unroll
    for (int jj = 0; jj < 12; ++jj) {
      float wv = wr[jj];
      pacc[0][jj] += a0 * wv;
      pacc[1][jj] += a1 * wv;
      pacc[2][jj] += a2 * wv;
      pacc[3][jj] += a3 * wv;
    }
  }
#pragma unroll
  for (int i = 0; i < 4; ++i) {
    size_t o = pbase + (size_t)(rg * 4 + i) * CC + cg * 12;
#pragma unroll
    for (int jj = 0; jj < 12; ++jj) out[o + jj] = pacc[i][jj] + bias[jj];
  }
}

// ------------- kernel 5: dwconv -> gelu -> dwconv, += into out -------------
__global__ __launch_bounds__(256) void lcam_pos(const float* __restrict__ x,
                                                const float* __restrict__ w1,
                                                const float* __restrict__ w2,
                                                float* __restrict__ out) {
  __shared__ __align__(16) float xt[20 * 20 * 16];
  __shared__ float t1[18 * 18 * 16];
  __shared__ float wl1[16 * 9], wl2[16 * 9];
  int blk = blockIdx.x;             // b(2) * ty(16) * tx(16) * cg(12)
  int cgI = blk % 12; int tmp = blk / 12;
  int tx = tmp % 16; tmp /= 16;
  int ty = tmp % 16; int b = tmp / 16;
  int c0 = cgI * 16;
  int y0 = ty * 16, x0 = tx * 16;
  int t = threadIdx.x;
  if (t < 144) { wl1[t] = w1[c0 * 9 + t]; wl2[t] = w2[c0 * 9 + t]; }
  // stage x halo 20x20x16 (zero outside image = SAME zero pad)
  for (int vi = t; vi < 1600; vi += 256) {
    int cc4 = vi & 3;
    int lin = vi >> 2;
    int xx = lin % 20, yy = lin / 20;
    int gy = y0 - 2 + yy, gx = x0 - 2 + xx;
    float4 v = {0.f, 0.f, 0.f, 0.f};
    if (gy >= 0 && gy < HH && gx >= 0 && gx < WWD)
      v = *(const float4*)(x + (((size_t)b * HH + gy) * WWD + gx) * CC + c0 + cc4 * 4);
    *(float4*)(xt + (yy * 20 + xx) * 16 + cc4 * 4) = v;
  }
  __syncthreads();
  // conv1 + exact gelu -> t1 halo 18x18x16; force 0 outside image (conv2 zero-pads)
  for (int idx = t; idx < 5184; idx += 256) {
    int cc = idx & 15;
    int xx = (idx >> 4) % 18;
    int yy = idx / 288;
    int gy = y0 - 1 + yy, gx = x0 - 1 + xx;
    float r = 0.f;
    if (gy >= 0 && gy < HH && gx >= 0 && gx < WWD) {
#pragma unroll
      for (int ky = 0; ky < 3; ++ky)
#pragma unroll
        for (int kx = 0; kx < 3; ++kx)
          r += xt[((yy + ky) * 20 + xx + kx) * 16 + cc] * wl1[cc * 9 + ky * 3 + kx];
      r = 0.5f * r * (1.f + erff(r * 0.70710678118654752f));
    }
    t1[(yy * 18 + xx) * 16 + cc] = r;
  }
  __syncthreads();
  // conv2 + add into out
  for (int idx = t; idx < 4096; idx += 256) {
    int cc = idx & 15;
    int xx = (idx >> 4) & 15;
    int yy = idx >> 8;
    float r = 0.f;
#pragma unroll
    for (int ky = 0; ky < 3; ++ky)
#pragma unroll
      for (int kx = 0; kx < 3; ++kx)
        r += t1[((yy + ky) * 18 + xx + kx) * 16 + cc] * wl2[cc * 9 + ky * 3 + kx];
    size_t o = (((size_t)b * HH + y0 + yy) * WWD + x0 + xx) * CC + c0 + cc;
    out[o] += r;
  }
}

extern "C" void kernel_launch(void* const* d_in, const int* in_sizes, int n_in,
                              void* d_out, int out_size, void* d_ws, size_t ws_size,
                              hipStream_t stream) {
  const float* x       = (const float*)d_in[0];
  const float* illu    = (const float*)d_in[1];
  const float* gt_w    = (const float*)d_in[2];
  const float* gt_b    = (const float*)d_in[3];
  const float* qkv_w   = (const float*)d_in[4];
  const float* qkv_b   = (const float*)d_in[5];
  const float* proj_w  = (const float*)d_in[6];
  const float* proj_b  = (const float*)d_in[7];
  const float* conv1_w = (const float*)d_in[8];
  const float* conv2_w = (const float*)d_in[9];
  float* out = (float*)d_out;

  short* wf   = (short*)d_ws;                          // 110592 bf16 = 221184 B
  float* sums = (float*)((char*)d_ws + 221184);        // BB*CC floats
  float* gt   = sums + BB * CC;                        // BB*CC floats

  hipMemsetAsync(sums, 0, BB * CC * sizeof(float), stream);
  lcam_wshuf<<<54, 256, 0, stream>>>(qkv_w, wf);
  lcam_sum_x<<<1024, 256, 0, stream>>>(x, sums);
  lcam_gt<<<BB, CC, 0, stream>>>(sums, gt_w, gt_b, gt);
  lcam_attn<<<2048, 256, 0, stream>>>(x, illu, wf, qkv_b, gt, out);
  lcam_proj<<<2048, 256, 0, stream>>>(proj_w, proj_b, out);
  lcam_pos<<<6144, 256, 0, stream>>>(x, conv1_w, conv2_w, out);
}

// Round 3
// 548.652 us; speedup vs baseline: 5.6339x; 1.4258x over previous
//
#include <hip/hip_runtime.h>
#include <hip/hip_bf16.h>

#define BB   2
#define HH   256
#define WWD  256
#define CC   192
#define WSZ  8
#define TT   64
#define NHD  6
#define DHD  32
#define N3   576

typedef __attribute__((ext_vector_type(8))) short short8;
typedef __attribute__((ext_vector_type(4))) float f32x4;

__device__ inline short bf16_bits(float f) {
  __hip_bfloat16 h = __float2bfloat16(f);
  return __builtin_bit_cast(short, h);
}

// ---- kernel 0: pre-shuffle a row-major [K][ncols] weight into bf16 B-frags --
// frag gid = ct*384 + s*64 + lane; element j: B[k = s*32 + (lane>>4)*8 + j]
//                                             [col = ct*16 + (lane&15)]
__global__ __launch_bounds__(256) void lcam_wshuf(const float* __restrict__ src,
                                                  short* __restrict__ dst,
                                                  int ncols, int nfrag) {
  int gid = blockIdx.x * 256 + threadIdx.x;
  if (gid >= nfrag) return;
  int lane = gid & 63;
  int s = (gid >> 6) % 6;
  int ct = gid / 384;
  int col = ct * 16 + (lane & 15);
  int k0 = s * 32 + (lane >> 4) * 8;
  short8 v;
#pragma unroll
  for (int j = 0; j < 8; ++j)
    v[j] = bf16_bits(src[(size_t)(k0 + j) * ncols + col]);
  *(short8*)(dst + (size_t)gid * 8) = v;
}

// ---------------- kernel 1: spatial sum of x -> sums[b][c] ----------------
__global__ __launch_bounds__(256) void lcam_sum_x(const float* __restrict__ x,
                                                  float* __restrict__ sums) {
  int blk = blockIdx.x;            // 1024 blocks: 2 batches * 512 chunks of 128 px
  int b = blk >> 9;
  int chunk = blk & 511;
  const float* xp = x + ((size_t)b * 65536 + (size_t)chunk * 128) * CC;
  int t = threadIdx.x;
  if (t < CC) {
    float acc = 0.f;
    for (int p = 0; p < 128; ++p) acc += xp[(size_t)p * CC + t];
    atomicAdd(&sums[b * CC + t], acc);
  }
}

// ---------------- kernel 2: global token gt[b][c] ----------------
__global__ void lcam_gt(const float* __restrict__ sums,
                        const float* __restrict__ gt_w,
                        const float* __restrict__ gt_b,
                        float* __restrict__ gt) {
  int b = blockIdx.x;
  int co = threadIdx.x;            // 192 threads
  float acc = gt_b[co];
  const float inv = 1.f / 65536.f;
  for (int c = 0; c < CC; ++c)
    acc += sums[b * CC + c] * inv * gt_w[c * CC + co];
  gt[b * CC + co] = acc;
}

// ---- kernel 3: fully-fused window attention + projection, all-MFMA --------
__global__ __launch_bounds__(256) void lcam_attn(
    const float* __restrict__ x, const float* __restrict__ illu,
    const short* __restrict__ wf, const short* __restrict__ pwf,
    const float* __restrict__ qkv_b, const float* __restrict__ proj_b,
    const float* __restrict__ gt, float* __restrict__ out) {
  // bf16 LDS tiles; strides padded for 16B-aligned b128 frag reads, <=2-way banks
  __shared__ __align__(16) short qs[64 * 40];   // q  [query][dim] (scaled+normed)
  __shared__ __align__(16) short ks[80 * 40];   // k  [key][dim], row64 = gt; 65-79 garbage (masked)
  __shared__ __align__(16) short vt[32 * 72];   // v^T[dim][key]  (modulated)
  __shared__ __align__(16) short ps[64 * 88];   // P  [query][key 0..63]
  __shared__ __align__(16) short os[64 * 200];  // O  [pixel][192ch]

  int w = blockIdx.x;          // 2048 windows
  int b  = w >> 10;
  int wy = (w >> 5) & 31;
  int wx = w & 31;
  int t  = threadIdx.x;
  int lane = t & 63;
  int rtile = t >> 6;             // wave = 16-row tile
  int m = lane & 15;
  int quad = lane >> 4;
  int key0 = rtile * 16 + quad * 4;   // first C-layout row this lane owns

  size_t base = ((size_t)(b * HH + wy * WSZ) * WWD + wx * WSZ) * CC;

  // ---- preload x A-frags (bf16), reused across all heads ----
  int apix = rtile * 16 + m;
  size_t arow = base + (size_t)((apix >> 3) * WWD + (apix & 7)) * CC + quad * 8;
  short8 afrag[6];
#pragma unroll
  for (int s = 0; s < 6; ++s) {
    const float* ap = x + arow + s * 32;
    float4 f0 = *(const float4*)(ap);
    float4 f1 = *(const float4*)(ap + 4);
    short8 v;
    v[0] = bf16_bits(f0.x); v[1] = bf16_bits(f0.y);
    v[2] = bf16_bits(f0.z); v[3] = bf16_bits(f0.w);
    v[4] = bf16_bits(f1.x); v[5] = bf16_bits(f1.y);
    v[6] = bf16_bits(f1.z); v[7] = bf16_bits(f1.w);
    afrag[s] = v;
  }
  const short8* wf8 = (const short8*)wf;
  const short8* pwf8 = (const short8*)pwf;

  for (int h = 0; h < NHD; ++h) {
    __syncthreads();   // prior head's QK/PV reads done before new tile writes
    // ============ qkv via MFMA; epilogues in C-layout registers ============
    // ---- Q (ct = 2h, 2h+1): bias -> l2norm -> fold softmax scale -> qs bf16
    {
      f32x4 a0 = {0.f,0.f,0.f,0.f}, a1 = {0.f,0.f,0.f,0.f};
#pragma unroll
      for (int s = 0; s < 6; ++s)
        a0 = __builtin_amdgcn_mfma_f32_16x16x32_bf16(afrag[s], wf8[(2*h)*384 + s*64 + lane], a0, 0,0,0);
#pragma unroll
      for (int s = 0; s < 6; ++s)
        a1 = __builtin_amdgcn_mfma_f32_16x16x32_bf16(afrag[s], wf8[(2*h+1)*384 + s*64 + lane], a1, 0,0,0);
      float b0 = qkv_b[h*32 + m], b1 = qkv_b[h*32 + 16 + m];
#pragma unroll
      for (int r = 0; r < 4; ++r) {
        float v0 = a0[r] + b0, v1 = a1[r] + b1;
        float ss = v0*v0 + v1*v1;
        ss += __shfl_xor(ss, 1); ss += __shfl_xor(ss, 2);
        ss += __shfl_xor(ss, 4); ss += __shfl_xor(ss, 8);
        float scl = 0.17677669529663688f / fmaxf(sqrtf(ss), 1e-12f);
        int row = key0 + r;
        qs[row*40 + m]      = bf16_bits(v0 * scl);
        qs[row*40 + 16 + m] = bf16_bits(v1 * scl);
      }
    }
    // ---- K (ct = 12+2h, 12+2h+1): bias -> l2norm -> ks bf16
    {
      f32x4 a0 = {0.f,0.f,0.f,0.f}, a1 = {0.f,0.f,0.f,0.f};
#pragma unroll
      for (int s = 0; s < 6; ++s)
        a0 = __builtin_amdgcn_mfma_f32_16x16x32_bf16(afrag[s], wf8[(12+2*h)*384 + s*64 + lane], a0, 0,0,0);
#pragma unroll
      for (int s = 0; s < 6; ++s)
        a1 = __builtin_amdgcn_mfma_f32_16x16x32_bf16(afrag[s], wf8[(13+2*h)*384 + s*64 + lane], a1, 0,0,0);
      float b0 = qkv_b[192 + h*32 + m], b1 = qkv_b[192 + h*32 + 16 + m];
#pragma unroll
      for (int r = 0; r < 4; ++r) {
        float v0 = a0[r] + b0, v1 = a1[r] + b1;
        float ss = v0*v0 + v1*v1;
        ss += __shfl_xor(ss, 1); ss += __shfl_xor(ss, 2);
        ss += __shfl_xor(ss, 4); ss += __shfl_xor(ss, 8);
        float scl = 1.f / fmaxf(sqrtf(ss), 1e-12f);
        int row = key0 + r;
        ks[row*40 + m]      = bf16_bits(v0 * scl);
        ks[row*40 + 16 + m] = bf16_bits(v1 * scl);
      }
    }
    // ---- V (ct = 24+2h, 24+2h+1): bias -> *(1+sigmoid(illu)) -> vt bf16 (transposed)
    {
      f32x4 a0 = {0.f,0.f,0.f,0.f}, a1 = {0.f,0.f,0.f,0.f};
#pragma unroll
      for (int s = 0; s < 6; ++s)
        a0 = __builtin_amdgcn_mfma_f32_16x16x32_bf16(afrag[s], wf8[(24+2*h)*384 + s*64 + lane], a0, 0,0,0);
#pragma unroll
      for (int s = 0; s < 6; ++s)
        a1 = __builtin_amdgcn_mfma_f32_16x16x32_bf16(afrag[s], wf8[(25+2*h)*384 + s*64 + lane], a1, 0,0,0);
      float b0 = qkv_b[384 + h*32 + m], b1 = qkv_b[384 + h*32 + 16 + m];
#pragma unroll
      for (int r = 0; r < 4; ++r) {
        int key = key0 + r;
        const float* ip = illu + base + (size_t)((key >> 3) * WWD + (key & 7)) * CC + h*32;
        float i0 = ip[m], i1 = ip[16 + m];
        float s0 = 1.f / (1.f + expf(-i0));
        float s1 = 1.f / (1.f + expf(-i1));
        vt[m*72 + key]        = bf16_bits((a0[r] + b0) * (1.f + s0));
        vt[(16 + m)*72 + key] = bf16_bits((a1[r] + b1) * (1.f + s1));
      }
    }
    // global token = 65th key (raw gt, not normed/modulated)
    if (t < DHD) ks[64*40 + t] = bf16_bits(gt[b*CC + h*DHD + t]);
    __syncthreads();
    // ============ QK^T via MFMA (5 key tiles; tile 4 masked past key 64) ====
    short8 qa = *(const short8*)(qs + (rtile*16 + m)*40 + quad*8);
    f32x4 sc[5];
#pragma unroll
    for (int ct = 0; ct < 5; ++ct) {
      short8 kb = *(const short8*)(ks + (ct*16 + m)*40 + quad*8);
      f32x4 z = {0.f,0.f,0.f,0.f};
      sc[ct] = __builtin_amdgcn_mfma_f32_16x16x32_bf16(qa, kb, z, 0,0,0);
    }
    // ============ softmax in C-layout regs; P -> ps bf16 ============
    float p64v[4];
#pragma unroll
    for (int r = 0; r < 4; ++r) {
      float s4 = (m == 0) ? sc[4][r] : -1e30f;   // only key 64 valid in tile 4
      float mx = fmaxf(fmaxf(fmaxf(sc[0][r], sc[1][r]), fmaxf(sc[2][r], sc[3][r])), s4);
      mx = fmaxf(mx, __shfl_xor(mx, 1)); mx = fmaxf(mx, __shfl_xor(mx, 2));
      mx = fmaxf(mx, __shfl_xor(mx, 4)); mx = fmaxf(mx, __shfl_xor(mx, 8));
      float e0 = expf(sc[0][r] - mx), e1 = expf(sc[1][r] - mx);
      float e2 = expf(sc[2][r] - mx), e3 = expf(sc[3][r] - mx);
      float e4 = (m == 0) ? expf(s4 - mx) : 0.f;
      float sum = e0 + e1 + e2 + e3 + e4;
      sum += __shfl_xor(sum, 1); sum += __shfl_xor(sum, 2);
      sum += __shfl_xor(sum, 4); sum += __shfl_xor(sum, 8);
      float inv = 1.f / sum;
      int row = key0 + r;
      ps[row*88 + m]      = bf16_bits(e0 * inv);
      ps[row*88 + 16 + m] = bf16_bits(e1 * inv);
      ps[row*88 + 32 + m] = bf16_bits(e2 * inv);
      ps[row*88 + 48 + m] = bf16_bits(e3 * inv);
      p64v[r] = e4 * inv;
    }
    // ============ PV via MFMA (keys 0..63) + rank-1 global-token update =====
    f32x4 o0 = {0.f,0.f,0.f,0.f}, o1 = {0.f,0.f,0.f,0.f};
#pragma unroll
    for (int kc = 0; kc < 2; ++kc) {
      short8 pa  = *(const short8*)(ps + (rtile*16 + m)*88 + kc*32 + quad*8);
      short8 vb0 = *(const short8*)(vt + m*72        + kc*32 + quad*8);
      short8 vb1 = *(const short8*)(vt + (16 + m)*72 + kc*32 + quad*8);
      o0 = __builtin_amdgcn_mfma_f32_16x16x32_bf16(pa, vb0, o0, 0,0,0);
      o1 = __builtin_amdgcn_mfma_f32_16x16x32_bf16(pa, vb1, o1, 0,0,0);
    }
    float gv0 = gt[b*CC + h*32 + m];
    float gv1 = gt[b*CC + h*32 + 16 + m];
#pragma unroll
    for (int r = 0; r < 4; ++r) {
      float pr = __shfl(p64v[r], lane & 48);   // broadcast from lane m==0 of quad
      int row = key0 + r;
      os[row*200 + h*32 + m]      = bf16_bits(o0[r] + pr * gv0);
      os[row*200 + h*32 + 16 + m] = bf16_bits(o1[r] + pr * gv1);
    }
  }
  __syncthreads();
  // ============ fused projection: O[64x192] @ proj_w + proj_b ============
  short8 af[6];
#pragma unroll
  for (int s = 0; s < 6; ++s)
    af[s] = *(const short8*)(os + (rtile*16 + m)*200 + s*32 + quad*8);
#pragma unroll
  for (int ct = 0; ct < 12; ++ct) {
    f32x4 acc = {0.f,0.f,0.f,0.f};
#pragma unroll
    for (int s = 0; s < 6; ++s)
      acc = __builtin_amdgcn_mfma_f32_16x16x32_bf16(af[s], pwf8[ct*384 + s*64 + lane], acc, 0,0,0);
    float bias = proj_b[ct*16 + m];
#pragma unroll
    for (int r = 0; r < 4; ++r) {
      int row = key0 + r;
      out[base + (size_t)((row >> 3) * WWD + (row & 7)) * CC + ct*16 + m] = acc[r] + bias;
    }
  }
}

// ------------- kernel 5: dwconv -> gelu -> dwconv, += into out -------------
__global__ __launch_bounds__(256) void lcam_pos(const float* __restrict__ x,
                                                const float* __restrict__ w1,
                                                const float* __restrict__ w2,
                                                float* __restrict__ out) {
  __shared__ __align__(16) float xt[20 * 20 * 16];
  __shared__ float t1[18 * 18 * 16];
  __shared__ float wl1[16 * 9], wl2[16 * 9];
  int blk = blockIdx.x;             // b(2) * ty(16) * tx(16) * cg(12)
  int cgI = blk % 12; int tmp = blk / 12;
  int tx = tmp % 16; tmp /= 16;
  int ty = tmp % 16; int b = tmp / 16;
  int c0 = cgI * 16;
  int y0 = ty * 16, x0 = tx * 16;
  int t = threadIdx.x;
  if (t < 144) { wl1[t] = w1[c0 * 9 + t]; wl2[t] = w2[c0 * 9 + t]; }
  // stage x halo 20x20x16 (zero outside image = SAME zero pad)
  for (int vi = t; vi < 1600; vi += 256) {
    int cc4 = vi & 3;
    int lin = vi >> 2;
    int xx = lin % 20, yy = lin / 20;
    int gy = y0 - 2 + yy, gx = x0 - 2 + xx;
    float4 v = {0.f, 0.f, 0.f, 0.f};
    if (gy >= 0 && gy < HH && gx >= 0 && gx < WWD)
      v = *(const float4*)(x + (((size_t)b * HH + gy) * WWD + gx) * CC + c0 + cc4 * 4);
    *(float4*)(xt + (yy * 20 + xx) * 16 + cc4 * 4) = v;
  }
  __syncthreads();
  // conv1 + exact gelu -> t1 halo 18x18x16; force 0 outside image (conv2 zero-pads)
  for (int idx = t; idx < 5184; idx += 256) {
    int cc = idx & 15;
    int xx = (idx >> 4) % 18;
    int yy = idx / 288;
    int gy = y0 - 1 + yy, gx = x0 - 1 + xx;
    float r = 0.f;
    if (gy >= 0 && gy < HH && gx >= 0 && gx < WWD) {
#pragma unroll
      for (int ky = 0; ky < 3; ++ky)
#pragma unroll
        for (int kx = 0; kx < 3; ++kx)
          r += xt[((yy + ky) * 20 + xx + kx) * 16 + cc] * wl1[cc * 9 + ky * 3 + kx];
      r = 0.5f * r * (1.f + erff(r * 0.70710678118654752f));
    }
    t1[(yy * 18 + xx) * 16 + cc] = r;
  }
  __syncthreads();
  // conv2 + add into out
  for (int idx = t; idx < 4096; idx += 256) {
    int cc = idx & 15;
    int xx = (idx >> 4) & 15;
    int yy = idx >> 8;
    float r = 0.f;
#pragma unroll
    for (int ky = 0; ky < 3; ++ky)
#pragma unroll
      for (int kx = 0; kx < 3; ++kx)
        r += t1[((yy + ky) * 18 + xx + kx) * 16 + cc] * wl2[cc * 9 + ky * 3 + kx];
    size_t o = (((size_t)b * HH + y0 + yy) * WWD + x0 + xx) * CC + c0 + cc;
    out[o] += r;
  }
}

extern "C" void kernel_launch(void* const* d_in, const int* in_sizes, int n_in,
                              void* d_out, int out_size, void* d_ws, size_t ws_size,
                              hipStream_t stream) {
  const float* x       = (const float*)d_in[0];
  const float* illu    = (const float*)d_in[1];
  const float* gt_w    = (const float*)d_in[2];
  const float* gt_b    = (const float*)d_in[3];
  const float* qkv_w   = (const float*)d_in[4];
  const float* qkv_b   = (const float*)d_in[5];
  const float* proj_w  = (const float*)d_in[6];
  const float* proj_b  = (const float*)d_in[7];
  const float* conv1_w = (const float*)d_in[8];
  const float* conv2_w = (const float*)d_in[9];
  float* out = (float*)d_out;

  short* wf   = (short*)d_ws;                          // 36*6*64*8 bf16 = 221184 B
  short* pwf  = (short*)((char*)d_ws + 221184);        // 12*6*64*8 bf16 =  73728 B
  float* sums = (float*)((char*)d_ws + 221184 + 73728);
  float* gt   = sums + BB * CC;

  hipMemsetAsync(sums, 0, BB * CC * sizeof(float), stream);
  lcam_wshuf<<<54, 256, 0, stream>>>(qkv_w, wf, N3, 36 * 6 * 64);
  lcam_wshuf<<<18, 256, 0, stream>>>(proj_w, pwf, CC, 12 * 6 * 64);
  lcam_sum_x<<<1024, 256, 0, stream>>>(x, sums);
  lcam_gt<<<BB, CC, 0, stream>>>(sums, gt_w, gt_b, gt);
  lcam_attn<<<2048, 256, 0, stream>>>(x, illu, wf, pwf, qkv_b, proj_b, gt, out);
  lcam_pos<<<6144, 256, 0, stream>>>(x, conv1_w, conv2_w, out);
}